// Round 11
// baseline (176.251 us; speedup 1.0000x reference)
//
#include <hip/hip_runtime.h>

#define N_NODES 50000
#define N_EDGES 600000
#define E_TOT   650000   // edges + self loops
#define NBLK    196      // ceil(N_NODES/256)

typedef __attribute__((ext_vector_type(8))) short short8;
typedef __attribute__((ext_vector_type(4))) float f32x4;

__device__ inline short f2bf(float f) {           // round-to-nearest-even f32->bf16
  union { float f; unsigned u; } v; v.f = f;
  unsigned r = (v.u + 0x7FFFu + ((v.u >> 16) & 1u)) >> 16;
  return (short)r;
}
__device__ inline float bf2f(short u) {
  union { unsigned u; float f; } v; v.u = ((unsigned)(unsigned short)u) << 16;
  return v.f;
}

// ---------------------------------------------------------------- CSR build

__global__ void degree_kernel(const int* __restrict__ ei, int* __restrict__ deg) {
  int e = blockIdx.x * blockDim.x + threadIdx.x;
  if (e >= E_TOT) return;
  int d = (e < N_EDGES) ? ei[N_EDGES + e] : (e - N_EDGES);
  atomicAdd(&deg[d], 1);
}

// per-block sums for indptr scan + LDS-aggregated degree histogram (64 bins)
__global__ __launch_bounds__(256) void bsum_kernel(const int* __restrict__ deg,
                                                   int* __restrict__ bsum,
                                                   int* __restrict__ dhist) {
  __shared__ int ws[4];
  __shared__ int lh[64];
  int t = threadIdx.x;
  int i = blockIdx.x * 256 + t;
  if (t < 64) lh[t] = 0;
  __syncthreads();
  int v = (i < N_NODES) ? deg[i] : 0;
  if (i < N_NODES) atomicAdd(&lh[min(v, 63)], 1);
  int r = v;
  #pragma unroll
  for (int off = 32; off > 0; off >>= 1) r += __shfl_down(r, off);
  if ((t & 63) == 0) ws[t >> 6] = r;
  __syncthreads();
  if (t == 0) bsum[blockIdx.x] = ws[0] + ws[1] + ws[2] + ws[3];
  if (t < 64 && lh[t]) atomicAdd(&dhist[t], lh[t]);
}

// block-offset scan + degree-bin base scan (both tiny, one block)
__global__ __launch_bounds__(256) void boff_kernel(const int* __restrict__ bsum,
                                                   int* __restrict__ boff,
                                                   const int* __restrict__ dhist,
                                                   int* __restrict__ dbase) {
  int t = threadIdx.x;
  int orig = (t < NBLK) ? bsum[t] : 0;
  int v = orig;
  int lane = t & 63, wid = t >> 6;
  #pragma unroll
  for (int off = 1; off < 64; off <<= 1) {
    int u = __shfl_up(v, off);
    if (lane >= off) v += u;
  }
  __shared__ int ws[4];
  if (lane == 63) ws[wid] = v;
  __syncthreads();
  if (t == 0) { int a = 0; for (int w = 0; w < 4; ++w) { int tmp = ws[w]; ws[w] = a; a += tmp; } }
  __syncthreads();
  int incl = v + ws[wid];
  if (t < NBLK) boff[t] = incl - orig;
  // degree-bin exclusive scan (wave 0 only: t == lane for t<64)
  if (t < 64) {
    int hv = dhist[t];
    int s = hv;
    #pragma unroll
    for (int off = 1; off < 64; off <<= 1) {
      int u = __shfl_up(s, off);
      if (t >= off) s += u;
    }
    dbase[t] = s - hv;
  }
}

// indptr + counting-sort scatter of node ids by degree -> order[]
__global__ __launch_bounds__(256) void indptr_kernel(const int* __restrict__ deg,
                                                     const int* __restrict__ boff,
                                                     int* __restrict__ indptr,
                                                     const int* __restrict__ dbase,
                                                     int* __restrict__ dfill,
                                                     int* __restrict__ order) {
  __shared__ int ws[4];
  __shared__ int lh2[64];
  __shared__ int gbs[64];
  int b = blockIdx.x, t = threadIdx.x;
  int i = b * 256 + t;
  if (t < 64) lh2[t] = 0;
  __syncthreads();
  int d = (i < N_NODES) ? deg[i] : 0;
  int dm = min(d, 63), lrank = 0;
  if (i < N_NODES) lrank = atomicAdd(&lh2[dm], 1);
  int v = d;
  int lane = t & 63, wid = t >> 6;
  #pragma unroll
  for (int off = 1; off < 64; off <<= 1) {
    int u = __shfl_up(v, off);
    if (lane >= off) v += u;
  }
  if (lane == 63) ws[wid] = v;
  __syncthreads();
  if (t == 0) { int a = 0; for (int w = 0; w < 4; ++w) { int tmp = ws[w]; ws[w] = a; a += tmp; } }
  if (t < 64) gbs[t] = lh2[t] ? atomicAdd(&dfill[t], lh2[t]) : 0;
  __syncthreads();
  int incl = v + ws[wid] + boff[b];
  if (i < N_NODES) indptr[i] = incl - d;
  if (i == N_NODES - 1) indptr[N_NODES] = incl;
  if (i < N_NODES) order[dbase[dm] + gbs[dm] + lrank] = i;
}

__global__ void scatter_kernel(const int* __restrict__ ei, const int* __restrict__ indptr,
                               int* __restrict__ fill, int* __restrict__ csr_src) {
  int e = blockIdx.x * blockDim.x + threadIdx.x;
  if (e >= E_TOT) return;
  int s, d;
  if (e < N_EDGES) { s = ei[e]; d = ei[N_EDGES + e]; }
  else             { s = e - N_EDGES; d = s; }
  int pos = indptr[d] + atomicAdd(&fill[d], 1);
  csr_src[pos] = s;
}

// ---------------------------------------------------------------- W prep: f32 [128k][128c] x2 -> bf16 [256c][128k]

__global__ __launch_bounds__(256) void wprep_kernel(const float* __restrict__ Wl,
                                                    const float* __restrict__ Wr,
                                                    short* __restrict__ Wbf) {
  int gid = blockIdx.x * 256 + threadIdx.x;   // 4096 threads: 256 cols x 16 k-chunks
  int c = gid >> 4, k8 = (gid & 15) * 8;
  const float* W = (c < 128) ? Wl : Wr;
  int cc = c & 127;
  short8 o;
  #pragma unroll
  for (int j = 0; j < 8; ++j) o[j] = f2bf(W[(size_t)(k8 + j) * 128 + cc]);
  *(short8*)(Wbf + (size_t)c * 128 + k8) = o;
}

// ---------------------------------------------------------------- layer 1 GEMM via bf16 MFMA
// ONE dispatch: As (x tile) staged once; Bs restaged per half (Wl then Wr).

#define LSWZ(row, k) (((row) * 128 + (k)) ^ (((row) & 7) << 3))

__global__ __launch_bounds__(256) void gemm1_mfma(
    const float* __restrict__ x, const short* __restrict__ Wbf,
    const float* __restrict__ bl, const float* __restrict__ br,
    short* __restrict__ xl, short* __restrict__ xr) {
  __shared__ short As[128 * 128];
  __shared__ short Bs[128 * 128];
  int t = threadIdx.x;
  int row0 = blockIdx.x * 128;

  #pragma unroll
  for (int i = 0; i < 8; ++i) {
    int c = t + 256 * i;               // 2048 chunks of 8 elems
    int r = c >> 4, k8 = (c & 15) * 8;
    int gr = row0 + r;
    short8 o = {};
    if (gr < N_NODES) {
      const float* p = x + (size_t)gr * 128 + k8;
      f32x4 a = *(const f32x4*)p, b = *(const f32x4*)(p + 4);
      o[0] = f2bf(a.x); o[1] = f2bf(a.y); o[2] = f2bf(a.z); o[3] = f2bf(a.w);
      o[4] = f2bf(b.x); o[5] = f2bf(b.y); o[6] = f2bf(b.z); o[7] = f2bf(b.w);
    }
    *(short8*)(&As[LSWZ(r, k8)]) = o;
  }

  int w = t >> 6, lane = t & 63;
  int wm = (w >> 1) * 64, wn = (w & 1) * 64;
  int lr = lane & 15, lk = (lane >> 4) * 8;

  for (int hb = 0; hb < 2; ++hb) {
    #pragma unroll
    for (int i = 0; i < 8; ++i) {
      int c = t + 256 * i;
      int col = c >> 4, k8 = (c & 15) * 8;
      short8 o = *(const short8*)(Wbf + (size_t)(hb * 128 + col) * 128 + k8);
      *(short8*)(&Bs[LSWZ(col, k8)]) = o;
    }
    __syncthreads();

    f32x4 acc[4][4];
    #pragma unroll
    for (int m = 0; m < 4; ++m)
      #pragma unroll
      for (int n = 0; n < 4; ++n) acc[m][n] = (f32x4){0.f, 0.f, 0.f, 0.f};

    #pragma unroll
    for (int ks = 0; ks < 4; ++ks) {
      int k0 = ks * 32 + lk;
      short8 af[4], bfr[4];
      #pragma unroll
      for (int m = 0; m < 4; ++m) {
        int r = wm + m * 16 + lr;
        af[m] = *(const short8*)(&As[LSWZ(r, k0)]);
      }
      #pragma unroll
      for (int n = 0; n < 4; ++n) {
        int r = wn + n * 16 + lr;
        bfr[n] = *(const short8*)(&Bs[LSWZ(r, k0)]);
      }
      #pragma unroll
      for (int m = 0; m < 4; ++m)
        #pragma unroll
        for (int n = 0; n < 4; ++n)
          acc[m][n] = __builtin_amdgcn_mfma_f32_16x16x32_bf16(af[m], bfr[n], acc[m][n], 0, 0, 0);
    }

    const float* B0 = hb ? br : bl;
    short* O = hb ? xr : xl;
    int orow = (lane >> 4) * 4;
    #pragma unroll
    for (int n = 0; n < 4; ++n) {
      int col = wn + n * 16 + lr;
      float bv = B0[col];
      #pragma unroll
      for (int m = 0; m < 4; ++m) {
        #pragma unroll
        for (int r = 0; r < 4; ++r) {
          int grow = row0 + wm + m * 16 + orow + r;
          if (grow < N_NODES) O[(size_t)grow * 128 + col] = f2bf(acc[m][n][r] + bv);
        }
      }
    }
    __syncthreads();   // all waves done reading Bs before restage
  }
}

// ---------------------------------------------------------------- layer 1 attention+aggregation fused with layer-2 GEMV
// 16 lanes per node, nodes processed in DEGREE-SORTED order (order[]): the 4
// nodes sharing a wave have near-equal degree -> minimal union-iteration waste.
// Per 8-edge tile: gathers go global->LDS via global_load_lds (zero VGPR).

__global__ __launch_bounds__(256) void agg1_fused(
    const short* __restrict__ xl1, const short* __restrict__ xr1,
    const float* __restrict__ att, const float* __restrict__ bias,
    const float* __restrict__ Wl2, const float* __restrict__ bl2,
    const float* __restrict__ Wr2, const float* __restrict__ br2,
    const int* __restrict__ indptr, const int* __restrict__ csr_src,
    const int* __restrict__ order,
    float* __restrict__ xl2, float* __restrict__ xr2) {
  __shared__ short sbuf[4][8][512];    // [wave][slot][64 lanes x 8 shorts] = 32 KB
  int gid = blockIdx.x * 256 + threadIdx.x;
  int node = order[gid >> 4];          // grid exact: 3125 blocks * 16 nodes
  int t = threadIdx.x;
  int wid = t >> 6, lane = t & 63;
  int L = lane & 15;
  int gbase = lane & 48;               // wave-lane base of this 16-lane group

  short8 xr8 = *(const short8*)(xr1 + (size_t)node * 128 + L * 8);
  float xr[8], at[8];
  #pragma unroll
  for (int r = 0; r < 8; ++r) xr[r] = bf2f(xr8[r]);
  *(float4*)(at)     = *(const float4*)(att + L * 8);
  *(float4*)(at + 4) = *(const float4*)(att + L * 8 + 4);

  float m = -1e30f, denom = 0.f;
  float acc[8];
  #pragma unroll
  for (int r = 0; r < 8; ++r) acc[r] = 0.f;

  int p0 = indptr[node], p1 = indptr[node + 1];

  for (int base = p0; base < p1; base += 8) {
    // ONE coalesced index load: lane L holds edge (base+L)'s src for its node
    int pE = base + L;
    int myidx = csr_src[pE < p1 ? pE : p1 - 1];
    // 8 gathers global->LDS, all in flight, zero VGPR held
    #pragma unroll
    for (int j = 0; j < 8; ++j) {
      int ij = __shfl(myidx, gbase + j);
      const short* gp = xl1 + (size_t)ij * 128 + L * 8;
      __builtin_amdgcn_global_load_lds(
          (const __attribute__((address_space(1))) void*)gp,
          (__attribute__((address_space(3))) void*)&sbuf[wid][j][0],
          16, 0, 0);
    }
    asm volatile("s_waitcnt vmcnt(0)" ::: "memory");
    __builtin_amdgcn_sched_barrier(0);

    // 8 alpha dots (read own 16B slice back from LDS)
    float pa[8];
    #pragma unroll
    for (int j = 0; j < 8; ++j) {
      short8 v = *(const short8*)(&sbuf[wid][j][lane * 8]);
      float s = 0.f;
      #pragma unroll
      for (int r = 0; r < 8; ++r) {
        float e = bf2f(v[r]) + xr[r];
        e = fmaxf(e, 0.2f * e);          // leaky_relu 0.2, exact
        s = fmaf(e, at[r], s);
      }
      pa[j] = s;
    }
    // pipelined shuffle reductions (24 independent DS ops)
    #pragma unroll
    for (int st = 1; st < 8; st <<= 1) {
      #pragma unroll
      for (int j = 0; j < 8; ++j) pa[j] += __shfl_xor(pa[j], st);
    }
    // mask padded slots branchlessly (exp underflows to exact 0)
    #pragma unroll
    for (int j = 0; j < 8; ++j) pa[j] = (base + j < p1) ? pa[j] : -1e30f;
    // ONE online-softmax fold per tile
    float bm = pa[0];
    #pragma unroll
    for (int j = 1; j < 8; ++j) bm = fmaxf(bm, pa[j]);
    float mnew  = fmaxf(m, bm);
    float scale = __expf(m - mnew);
    float wgt[8], dsum = 0.f;
    #pragma unroll
    for (int j = 0; j < 8; ++j) { wgt[j] = __expf(pa[j] - mnew); dsum += wgt[j]; }
    denom = denom * scale + dsum;
    #pragma unroll
    for (int r = 0; r < 8; ++r) acc[r] *= scale;
    #pragma unroll
    for (int j = 0; j < 8; ++j) {
      short8 v = *(const short8*)(&sbuf[wid][j][lane * 8]);
      #pragma unroll
      for (int r = 0; r < 8; ++r) acc[r] = fmaf(wgt[j], bf2f(v[r]), acc[r]);
    }
    m = mnew;
  }

  float inv = 1.f / (denom + 1e-16f);
  float o[8];
  #pragma unroll
  for (int r = 0; r < 8; ++r) {
    float v = acc[r] * inv + bias[L * 8 + r];
    o[r] = fmaxf(v, 0.01f * v);         // post-layer LeakyReLU(0.01), exact
  }
  // fused layer-2 linear: lane L holds h[L*8 .. L*8+7]
  float pl[4] = {0.f, 0.f, 0.f, 0.f}, pr[4] = {0.f, 0.f, 0.f, 0.f};
  #pragma unroll
  for (int r = 0; r < 8; ++r) {
    float4 wl = *(const float4*)(Wl2 + (size_t)(L * 8 + r) * 4);
    float4 wr = *(const float4*)(Wr2 + (size_t)(L * 8 + r) * 4);
    pl[0] += o[r] * wl.x;  pl[1] += o[r] * wl.y;  pl[2] += o[r] * wl.z;  pl[3] += o[r] * wl.w;
    pr[0] += o[r] * wr.x;  pr[1] += o[r] * wr.y;  pr[2] += o[r] * wr.z;  pr[3] += o[r] * wr.w;
  }
  #pragma unroll
  for (int off = 1; off < 16; off <<= 1) {
    #pragma unroll
    for (int c = 0; c < 4; ++c) {
      pl[c] += __shfl_xor(pl[c], off);
      pr[c] += __shfl_xor(pr[c], off);
    }
  }
  if (L == 0) {
    float4 b0 = *(const float4*)(bl2);
    float4 b1 = *(const float4*)(br2);
    *(float4*)(xl2 + (size_t)node * 4) =
        make_float4(pl[0] + b0.x, pl[1] + b0.y, pl[2] + b0.z, pl[3] + b0.w);
    *(float4*)(xr2 + (size_t)node * 4) =
        make_float4(pr[0] + b1.x, pr[1] + b1.y, pr[2] + b1.z, pr[3] + b1.w);
  }
}

// ---------------------------------------------------------------- layer 2 attention + final softmax

__global__ __launch_bounds__(256) void agg2_kernel(
    const float* __restrict__ xl2, const float* __restrict__ xr2,
    const float* __restrict__ att, const float* __restrict__ bias,
    const int* __restrict__ indptr, const int* __restrict__ csr_src,
    const int* __restrict__ order,
    float* __restrict__ out) {
  int gid = blockIdx.x * 256 + threadIdx.x;
  int slot = gid >> 4;
  if (slot >= N_NODES) return;
  int node = order[slot];
  int L = threadIdx.x & 15;
  float4 xr = *(const float4*)(xr2 + (size_t)node * 4);
  float4 at = *(const float4*)(att);
  float m = -1e30f, denom = 0.f;
  float4 acc = make_float4(0.f, 0.f, 0.f, 0.f);
  int p0 = indptr[node], p1 = indptr[node + 1];
  int nit = (p1 - p0 + 15) >> 4;
  int p = p0 + L;
  for (int it = 0; it < nit; ++it) {
    bool valid = p < p1;
    int s = csr_src[valid ? p : p1 - 1];
    float4 xv = *(const float4*)(xl2 + (size_t)s * 4);
    float e0 = xv.x + xr.x; e0 = fmaxf(e0, 0.2f * e0);
    float e1 = xv.y + xr.y; e1 = fmaxf(e1, 0.2f * e1);
    float e2 = xv.z + xr.z; e2 = fmaxf(e2, 0.2f * e2);
    float e3 = xv.w + xr.w; e3 = fmaxf(e3, 0.2f * e3);
    float pa = e0 * at.x + e1 * at.y + e2 * at.z + e3 * at.w;
    pa = valid ? pa : -1e30f;
    float mnew  = fmaxf(m, pa);
    float scale = __expf(m - mnew);
    float wgt   = __expf(pa - mnew);    // exact 0 for padded slots
    denom = denom * scale + wgt;
    acc.x = acc.x * scale + wgt * xv.x;
    acc.y = acc.y * scale + wgt * xv.y;
    acc.z = acc.z * scale + wgt * xv.z;
    acc.w = acc.w * scale + wgt * xv.w;
    m = mnew;
    p += 16;
  }
  #pragma unroll
  for (int off = 1; off < 16; off <<= 1) {
    float mo = __shfl_xor(m, off);
    float dn = __shfl_xor(denom, off);
    float ax = __shfl_xor(acc.x, off);
    float ay = __shfl_xor(acc.y, off);
    float az = __shfl_xor(acc.z, off);
    float aw = __shfl_xor(acc.w, off);
    float mnew = fmaxf(m, mo);
    float sa = __expf(m - mnew);
    float sb = __expf(mo - mnew);
    denom = denom * sa + dn * sb;
    acc.x = acc.x * sa + ax * sb;
    acc.y = acc.y * sa + ay * sb;
    acc.z = acc.z * sa + az * sb;
    acc.w = acc.w * sa + aw * sb;
    m = mnew;
  }
  if (L == 0) {
    float inv = 1.f / (denom + 1e-16f);
    float4 b = *(const float4*)(bias);
    float o0 = acc.x * inv + b.x;
    float o1 = acc.y * inv + b.y;
    float o2 = acc.z * inv + b.z;
    float o3 = acc.w * inv + b.w;
    float mx = fmaxf(fmaxf(o0, o1), fmaxf(o2, o3));
    float q0 = __expf(o0 - mx), q1 = __expf(o1 - mx), q2 = __expf(o2 - mx), q3 = __expf(o3 - mx);
    float r = 1.f / (q0 + q1 + q2 + q3);
    *(float4*)(out + (size_t)node * 4) = make_float4(q0 * r, q1 * r, q2 * r, q3 * r);
  }
}

// ---------------------------------------------------------------- launch

extern "C" void kernel_launch(void* const* d_in, const int* in_sizes, int n_in,
                              void* d_out, int out_size, void* d_ws, size_t ws_size,
                              hipStream_t stream) {
  (void)in_sizes; (void)n_in; (void)out_size; (void)ws_size;
  const float* x     = (const float*)d_in[0];
  const int*   ei    = (const int*)d_in[1];
  const float* Wl1   = (const float*)d_in[3];
  const float* bl1   = (const float*)d_in[4];
  const float* Wr1   = (const float*)d_in[5];
  const float* br1   = (const float*)d_in[6];
  const float* att1  = (const float*)d_in[7];
  const float* bias1 = (const float*)d_in[8];
  const float* Wl2   = (const float*)d_in[9];
  const float* bl2   = (const float*)d_in[10];
  const float* Wr2   = (const float*)d_in[11];
  const float* br2   = (const float*)d_in[12];
  const float* att2  = (const float*)d_in[13];
  const float* bias2 = (const float*)d_in[14];
  float* out = (float*)d_out;

  char* w = (char*)d_ws;
  auto alloc = [&](size_t bytes) -> char* {
    char* p = w;
    w += (bytes + 255) & ~(size_t)255;
    return p;
  };
  short* xl1    = (short*)alloc((size_t)N_NODES * 128 * 2);
  short* xr1    = (short*)alloc((size_t)N_NODES * 128 * 2);
  float* xl2    = (float*)alloc((size_t)N_NODES * 4 * 4);
  float* xr2    = (float*)alloc((size_t)N_NODES * 4 * 4);
  int*   deg    = (int*)alloc((size_t)N_NODES * 4);   // deg/fill/dhist/dfill adjacent:
  int*   fill   = (int*)alloc((size_t)N_NODES * 4);   // cleared with ONE memset
  int*   dhist  = (int*)alloc((size_t)64 * 4);
  int*   dfill  = (int*)alloc((size_t)64 * 4);
  int*   indptr = (int*)alloc((size_t)(N_NODES + 1) * 4);
  int*   csr    = (int*)alloc((size_t)E_TOT * 4);
  int*   bsum   = (int*)alloc((size_t)NBLK * 4);
  int*   boff   = (int*)alloc((size_t)NBLK * 4);
  int*   dbase  = (int*)alloc((size_t)64 * 4);
  int*   order  = (int*)alloc((size_t)N_NODES * 4);
  short* Wbf    = (short*)alloc((size_t)256 * 128 * 2);

  hipMemsetAsync(deg, 0, (char*)(dfill + 64) - (char*)deg, stream);

  degree_kernel<<<(E_TOT + 255) / 256, 256, 0, stream>>>(ei, deg);
  bsum_kernel<<<NBLK, 256, 0, stream>>>(deg, bsum, dhist);
  boff_kernel<<<1, 256, 0, stream>>>(bsum, boff, dhist, dbase);
  indptr_kernel<<<NBLK, 256, 0, stream>>>(deg, boff, indptr, dbase, dfill, order);
  scatter_kernel<<<(E_TOT + 255) / 256, 256, 0, stream>>>(ei, indptr, fill, csr);
  wprep_kernel<<<16, 256, 0, stream>>>(Wl1, Wr1, Wbf);
  gemm1_mfma<<<(N_NODES + 127) / 128, 256, 0, stream>>>(x, Wbf, bl1, br1, xl1, xr1);
  agg1_fused<<<(N_NODES * 16 + 255) / 256, 256, 0, stream>>>(
      xl1, xr1, att1, bias1, Wl2, bl2, Wr2, br2, indptr, csr, order, xl2, xr2);
  agg2_kernel<<<(N_NODES * 16 + 255) / 256, 256, 0, stream>>>(
      xl2, xr2, att2, bias2, indptr, csr, order, out);
}

// Round 12
// 141.317 us; speedup vs baseline: 1.2472x; 1.2472x over previous
//
#include <hip/hip_runtime.h>

#define N_NODES 50000
#define N_EDGES 600000
#define E_TOT   650000   // edges + self loops
#define EBLK    2540     // ceil(E_TOT/256)
#define MAXD    64       // ELL stride; max in-degree ~ Poisson(12)+1 << 64

typedef __attribute__((ext_vector_type(8))) short short8;
typedef __attribute__((ext_vector_type(4))) float f32x4;

__device__ inline short f2bf(float f) {           // round-to-nearest-even f32->bf16
  union { float f; unsigned u; } v; v.f = f;
  unsigned r = (v.u + 0x7FFFu + ((v.u >> 16) & 1u)) >> 16;
  return (short)r;
}
__device__ inline float bf2f(short u) {
  union { unsigned u; float f; } v; v.u = ((unsigned)(unsigned short)u) << 16;
  return v.f;
}

// ---------------------------------------------------------------- graph build (ELL) + W prep, one launch
// blocks [0, EBLK): scatter edges into ell[dst*64 + slot]; deg = slot counter
// blocks [EBLK, EBLK+16): transpose-convert Wl1|Wr1 f32 [128k][128c] -> bf16 [256c][128k]

__global__ __launch_bounds__(256) void build_kernel(
    const int* __restrict__ ei, int* __restrict__ deg, int* __restrict__ ell,
    const float* __restrict__ Wl, const float* __restrict__ Wr, short* __restrict__ Wbf) {
  int b = blockIdx.x;
  if (b < EBLK) {
    int e = b * 256 + threadIdx.x;
    if (e >= E_TOT) return;
    int s, d;
    if (e < N_EDGES) { s = ei[e]; d = ei[N_EDGES + e]; }
    else             { s = e - N_EDGES; d = s; }
    int pos = atomicAdd(&deg[d], 1);
    ell[d * MAXD + pos] = s;
  } else {
    int gid = (b - EBLK) * 256 + threadIdx.x;   // 4096 threads: 256 cols x 16 k-chunks
    int c = gid >> 4, k8 = (gid & 15) * 8;
    const float* W = (c < 128) ? Wl : Wr;
    int cc = c & 127;
    short8 o;
    #pragma unroll
    for (int j = 0; j < 8; ++j) o[j] = f2bf(W[(size_t)(k8 + j) * 128 + cc]);
    *(short8*)(Wbf + (size_t)c * 128 + k8) = o;
  }
}

// ---------------------------------------------------------------- layer 1 GEMM via bf16 MFMA
// ONE dispatch: As (x tile) staged once; Bs restaged per half (Wl then Wr).

#define LSWZ(row, k) (((row) * 128 + (k)) ^ (((row) & 7) << 3))

__global__ __launch_bounds__(256) void gemm1_mfma(
    const float* __restrict__ x, const short* __restrict__ Wbf,
    const float* __restrict__ bl, const float* __restrict__ br,
    short* __restrict__ xl, short* __restrict__ xr) {
  __shared__ short As[128 * 128];
  __shared__ short Bs[128 * 128];
  int t = threadIdx.x;
  int row0 = blockIdx.x * 128;

  #pragma unroll
  for (int i = 0; i < 8; ++i) {
    int c = t + 256 * i;               // 2048 chunks of 8 elems
    int r = c >> 4, k8 = (c & 15) * 8;
    int gr = row0 + r;
    short8 o = {};
    if (gr < N_NODES) {
      const float* p = x + (size_t)gr * 128 + k8;
      f32x4 a = *(const f32x4*)p, b = *(const f32x4*)(p + 4);
      o[0] = f2bf(a.x); o[1] = f2bf(a.y); o[2] = f2bf(a.z); o[3] = f2bf(a.w);
      o[4] = f2bf(b.x); o[5] = f2bf(b.y); o[6] = f2bf(b.z); o[7] = f2bf(b.w);
    }
    *(short8*)(&As[LSWZ(r, k8)]) = o;
  }

  int w = t >> 6, lane = t & 63;
  int wm = (w >> 1) * 64, wn = (w & 1) * 64;
  int lr = lane & 15, lk = (lane >> 4) * 8;

  for (int hb = 0; hb < 2; ++hb) {
    #pragma unroll
    for (int i = 0; i < 8; ++i) {
      int c = t + 256 * i;
      int col = c >> 4, k8 = (c & 15) * 8;
      short8 o = *(const short8*)(Wbf + (size_t)(hb * 128 + col) * 128 + k8);
      *(short8*)(&Bs[LSWZ(col, k8)]) = o;
    }
    __syncthreads();

    f32x4 acc[4][4];
    #pragma unroll
    for (int m = 0; m < 4; ++m)
      #pragma unroll
      for (int n = 0; n < 4; ++n) acc[m][n] = (f32x4){0.f, 0.f, 0.f, 0.f};

    #pragma unroll
    for (int ks = 0; ks < 4; ++ks) {
      int k0 = ks * 32 + lk;
      short8 af[4], bfr[4];
      #pragma unroll
      for (int m = 0; m < 4; ++m) {
        int r = wm + m * 16 + lr;
        af[m] = *(const short8*)(&As[LSWZ(r, k0)]);
      }
      #pragma unroll
      for (int n = 0; n < 4; ++n) {
        int r = wn + n * 16 + lr;
        bfr[n] = *(const short8*)(&Bs[LSWZ(r, k0)]);
      }
      #pragma unroll
      for (int m = 0; m < 4; ++m)
        #pragma unroll
        for (int n = 0; n < 4; ++n)
          acc[m][n] = __builtin_amdgcn_mfma_f32_16x16x32_bf16(af[m], bfr[n], acc[m][n], 0, 0, 0);
    }

    const float* B0 = hb ? br : bl;
    short* O = hb ? xr : xl;
    int orow = (lane >> 4) * 4;
    #pragma unroll
    for (int n = 0; n < 4; ++n) {
      int col = wn + n * 16 + lr;
      float bv = B0[col];
      #pragma unroll
      for (int m = 0; m < 4; ++m) {
        #pragma unroll
        for (int r = 0; r < 4; ++r) {
          int grow = row0 + wm + m * 16 + orow + r;
          if (grow < N_NODES) O[(size_t)grow * 128 + col] = f2bf(acc[m][n][r] + bv);
        }
      }
    }
    __syncthreads();   // all waves done reading Bs before restage
  }
}

// ---------------------------------------------------------------- layer 1 attention+aggregation fused with layer-2 GEMV
// 16 lanes per node. Per 8-edge tile: gathers go global->LDS via
// global_load_lds (per-lane global addr, wave-uniform LDS dest, zero VGPR for
// in-flight rows). Wave-private LDS slots: no __syncthreads, just vmcnt.

__global__ __launch_bounds__(256) void agg1_fused(
    const short* __restrict__ xl1, const short* __restrict__ xr1,
    const float* __restrict__ att, const float* __restrict__ bias,
    const float* __restrict__ Wl2, const float* __restrict__ bl2,
    const float* __restrict__ Wr2, const float* __restrict__ br2,
    const int* __restrict__ deg, const int* __restrict__ ell,
    float* __restrict__ xl2, float* __restrict__ xr2) {
  __shared__ short sbuf[4][8][512];    // [wave][slot][64 lanes x 8 shorts] = 32 KB
  int gid = blockIdx.x * 256 + threadIdx.x;
  int node = gid >> 4;                 // grid exact: 3125 blocks * 16 nodes
  int t = threadIdx.x;
  int wid = t >> 6, lane = t & 63;
  int L = lane & 15;
  int gbase = lane & 48;               // wave-lane base of this 16-lane group

  short8 xr8 = *(const short8*)(xr1 + (size_t)node * 128 + L * 8);
  float xr[8], at[8];
  #pragma unroll
  for (int r = 0; r < 8; ++r) xr[r] = bf2f(xr8[r]);
  *(float4*)(at)     = *(const float4*)(att + L * 8);
  *(float4*)(at + 4) = *(const float4*)(att + L * 8 + 4);

  float m = -1e30f, denom = 0.f;
  float acc[8];
  #pragma unroll
  for (int r = 0; r < 8; ++r) acc[r] = 0.f;

  int p1 = deg[node];
  const int* erow = ell + (size_t)node * MAXD;

  for (int base = 0; base < p1; base += 8) {
    // ONE coalesced index load: lane L holds edge (base+L)'s src for its node
    int pE = base + L;
    int myidx = erow[pE < p1 ? pE : p1 - 1];
    // 8 gathers global->LDS, all in flight, zero VGPR held
    #pragma unroll
    for (int j = 0; j < 8; ++j) {
      int ij = __shfl(myidx, gbase + j);
      const short* gp = xl1 + (size_t)ij * 128 + L * 8;
      __builtin_amdgcn_global_load_lds(
          (const __attribute__((address_space(1))) void*)gp,
          (__attribute__((address_space(3))) void*)&sbuf[wid][j][0],
          16, 0, 0);
    }
    asm volatile("s_waitcnt vmcnt(0)" ::: "memory");
    __builtin_amdgcn_sched_barrier(0);

    // 8 alpha dots (read own 16B slice back from LDS)
    float pa[8];
    #pragma unroll
    for (int j = 0; j < 8; ++j) {
      short8 v = *(const short8*)(&sbuf[wid][j][lane * 8]);
      float s = 0.f;
      #pragma unroll
      for (int r = 0; r < 8; ++r) {
        float e = bf2f(v[r]) + xr[r];
        e = fmaxf(e, 0.2f * e);          // leaky_relu 0.2, exact
        s = fmaf(e, at[r], s);
      }
      pa[j] = s;
    }
    // pipelined shuffle reductions (24 independent DS ops)
    #pragma unroll
    for (int st = 1; st < 8; st <<= 1) {
      #pragma unroll
      for (int j = 0; j < 8; ++j) pa[j] += __shfl_xor(pa[j], st);
    }
    // mask padded slots branchlessly (exp underflows to exact 0)
    #pragma unroll
    for (int j = 0; j < 8; ++j) pa[j] = (base + j < p1) ? pa[j] : -1e30f;
    // ONE online-softmax fold per tile
    float bm = pa[0];
    #pragma unroll
    for (int j = 1; j < 8; ++j) bm = fmaxf(bm, pa[j]);
    float mnew  = fmaxf(m, bm);
    float scale = __expf(m - mnew);
    float wgt[8], dsum = 0.f;
    #pragma unroll
    for (int j = 0; j < 8; ++j) { wgt[j] = __expf(pa[j] - mnew); dsum += wgt[j]; }
    denom = denom * scale + dsum;
    #pragma unroll
    for (int r = 0; r < 8; ++r) acc[r] *= scale;
    #pragma unroll
    for (int j = 0; j < 8; ++j) {
      short8 v = *(const short8*)(&sbuf[wid][j][lane * 8]);
      #pragma unroll
      for (int r = 0; r < 8; ++r) acc[r] = fmaf(wgt[j], bf2f(v[r]), acc[r]);
    }
    m = mnew;
  }

  float inv = 1.f / (denom + 1e-16f);
  float o[8];
  #pragma unroll
  for (int r = 0; r < 8; ++r) {
    float v = acc[r] * inv + bias[L * 8 + r];
    o[r] = fmaxf(v, 0.01f * v);         // post-layer LeakyReLU(0.01), exact
  }
  // fused layer-2 linear: lane L holds h[L*8 .. L*8+7]
  float pl[4] = {0.f, 0.f, 0.f, 0.f}, pr[4] = {0.f, 0.f, 0.f, 0.f};
  #pragma unroll
  for (int r = 0; r < 8; ++r) {
    float4 wl = *(const float4*)(Wl2 + (size_t)(L * 8 + r) * 4);
    float4 wr = *(const float4*)(Wr2 + (size_t)(L * 8 + r) * 4);
    pl[0] += o[r] * wl.x;  pl[1] += o[r] * wl.y;  pl[2] += o[r] * wl.z;  pl[3] += o[r] * wl.w;
    pr[0] += o[r] * wr.x;  pr[1] += o[r] * wr.y;  pr[2] += o[r] * wr.z;  pr[3] += o[r] * wr.w;
  }
  #pragma unroll
  for (int off = 1; off < 16; off <<= 1) {
    #pragma unroll
    for (int c = 0; c < 4; ++c) {
      pl[c] += __shfl_xor(pl[c], off);
      pr[c] += __shfl_xor(pr[c], off);
    }
  }
  if (L == 0) {
    float4 b0 = *(const float4*)(bl2);
    float4 b1 = *(const float4*)(br2);
    *(float4*)(xl2 + (size_t)node * 4) =
        make_float4(pl[0] + b0.x, pl[1] + b0.y, pl[2] + b0.z, pl[3] + b0.w);
    *(float4*)(xr2 + (size_t)node * 4) =
        make_float4(pr[0] + b1.x, pr[1] + b1.y, pr[2] + b1.z, pr[3] + b1.w);
  }
}

// ---------------------------------------------------------------- layer 2 attention + final softmax

__global__ __launch_bounds__(256) void agg2_kernel(
    const float* __restrict__ xl2, const float* __restrict__ xr2,
    const float* __restrict__ att, const float* __restrict__ bias,
    const int* __restrict__ deg, const int* __restrict__ ell,
    float* __restrict__ out) {
  int gid = blockIdx.x * 256 + threadIdx.x;
  int node = gid >> 4;
  if (node >= N_NODES) return;
  int L = threadIdx.x & 15;
  float4 xr = *(const float4*)(xr2 + (size_t)node * 4);
  float4 at = *(const float4*)(att);
  float m = -1e30f, denom = 0.f;
  float4 acc = make_float4(0.f, 0.f, 0.f, 0.f);
  int p1 = deg[node];
  const int* erow = ell + (size_t)node * MAXD;
  int nit = (p1 + 15) >> 4;
  int p = L;
  for (int it = 0; it < nit; ++it) {
    bool valid = p < p1;
    int s = erow[valid ? p : p1 - 1];
    float4 xv = *(const float4*)(xl2 + (size_t)s * 4);
    float e0 = xv.x + xr.x; e0 = fmaxf(e0, 0.2f * e0);
    float e1 = xv.y + xr.y; e1 = fmaxf(e1, 0.2f * e1);
    float e2 = xv.z + xr.z; e2 = fmaxf(e2, 0.2f * e2);
    float e3 = xv.w + xr.w; e3 = fmaxf(e3, 0.2f * e3);
    float pa = e0 * at.x + e1 * at.y + e2 * at.z + e3 * at.w;
    pa = valid ? pa : -1e30f;
    float mnew  = fmaxf(m, pa);
    float scale = __expf(m - mnew);
    float wgt   = __expf(pa - mnew);    // exact 0 for padded slots
    denom = denom * scale + wgt;
    acc.x = acc.x * scale + wgt * xv.x;
    acc.y = acc.y * scale + wgt * xv.y;
    acc.z = acc.z * scale + wgt * xv.z;
    acc.w = acc.w * scale + wgt * xv.w;
    m = mnew;
    p += 16;
  }
  #pragma unroll
  for (int off = 1; off < 16; off <<= 1) {
    float mo = __shfl_xor(m, off);
    float dn = __shfl_xor(denom, off);
    float ax = __shfl_xor(acc.x, off);
    float ay = __shfl_xor(acc.y, off);
    float az = __shfl_xor(acc.z, off);
    float aw = __shfl_xor(acc.w, off);
    float mnew = fmaxf(m, mo);
    float sa = __expf(m - mnew);
    float sb = __expf(mo - mnew);
    denom = denom * sa + dn * sb;
    acc.x = acc.x * sa + ax * sb;
    acc.y = acc.y * sa + ay * sb;
    acc.z = acc.z * sa + az * sb;
    acc.w = acc.w * sa + aw * sb;
    m = mnew;
  }
  if (L == 0) {
    float inv = 1.f / (denom + 1e-16f);
    float4 b = *(const float4*)(bias);
    float o0 = acc.x * inv + b.x;
    float o1 = acc.y * inv + b.y;
    float o2 = acc.z * inv + b.z;
    float o3 = acc.w * inv + b.w;
    float mx = fmaxf(fmaxf(o0, o1), fmaxf(o2, o3));
    float q0 = __expf(o0 - mx), q1 = __expf(o1 - mx), q2 = __expf(o2 - mx), q3 = __expf(o3 - mx);
    float r = 1.f / (q0 + q1 + q2 + q3);
    *(float4*)(out + (size_t)node * 4) = make_float4(q0 * r, q1 * r, q2 * r, q3 * r);
  }
}

// ---------------------------------------------------------------- launch (5 dispatches total)

extern "C" void kernel_launch(void* const* d_in, const int* in_sizes, int n_in,
                              void* d_out, int out_size, void* d_ws, size_t ws_size,
                              hipStream_t stream) {
  (void)in_sizes; (void)n_in; (void)out_size; (void)ws_size;
  const float* x     = (const float*)d_in[0];
  const int*   ei    = (const int*)d_in[1];
  const float* Wl1   = (const float*)d_in[3];
  const float* bl1   = (const float*)d_in[4];
  const float* Wr1   = (const float*)d_in[5];
  const float* br1   = (const float*)d_in[6];
  const float* att1  = (const float*)d_in[7];
  const float* bias1 = (const float*)d_in[8];
  const float* Wl2   = (const float*)d_in[9];
  const float* bl2   = (const float*)d_in[10];
  const float* Wr2   = (const float*)d_in[11];
  const float* br2   = (const float*)d_in[12];
  const float* att2  = (const float*)d_in[13];
  const float* bias2 = (const float*)d_in[14];
  float* out = (float*)d_out;

  char* w = (char*)d_ws;
  auto alloc = [&](size_t bytes) -> char* {
    char* p = w;
    w += (bytes + 255) & ~(size_t)255;
    return p;
  };
  short* xl1    = (short*)alloc((size_t)N_NODES * 128 * 2);
  short* xr1    = (short*)alloc((size_t)N_NODES * 128 * 2);
  float* xl2    = (float*)alloc((size_t)N_NODES * 4 * 4);
  float* xr2    = (float*)alloc((size_t)N_NODES * 4 * 4);
  int*   deg    = (int*)alloc((size_t)N_NODES * 4);
  int*   ell    = (int*)alloc((size_t)N_NODES * MAXD * 4);
  short* Wbf    = (short*)alloc((size_t)256 * 128 * 2);

  hipMemsetAsync(deg, 0, (size_t)N_NODES * 4, stream);

  build_kernel<<<EBLK + 16, 256, 0, stream>>>(ei, deg, ell, Wl1, Wr1, Wbf);
  gemm1_mfma<<<(N_NODES + 127) / 128, 256, 0, stream>>>(x, Wbf, bl1, br1, xl1, xr1);
  agg1_fused<<<(N_NODES * 16 + 255) / 256, 256, 0, stream>>>(
      xl1, xr1, att1, bias1, Wl2, bl2, Wr2, br2, deg, ell, xl2, xr2);
  agg2_kernel<<<(N_NODES * 16 + 255) / 256, 256, 0, stream>>>(
      xl2, xr2, att2, bias2, deg, ell, out);
}

// Round 13
// 128.167 us; speedup vs baseline: 1.3752x; 1.1026x over previous
//
#include <hip/hip_runtime.h>

#define N_NODES 50000
#define N_EDGES 600000
#define E_TOT   650000   // edges + self loops
#define EBLK    2540     // ceil(E_TOT/256)
#define GBLK    391      // ceil(N_NODES/128) gemm blocks
#define ZBLK    196      // ceil(N_NODES/256) deg-zero blocks
#define MAXD    64       // ELL stride; max in-degree ~ Poisson(12)+1 << 64

typedef __attribute__((ext_vector_type(8))) short short8;
typedef __attribute__((ext_vector_type(4))) float f32x4;

__device__ inline short f2bf(float f) {           // round-to-nearest-even f32->bf16
  union { float f; unsigned u; } v; v.f = f;
  unsigned r = (v.u + 0x7FFFu + ((v.u >> 16) & 1u)) >> 16;
  return (short)r;
}
__device__ inline float bf2f(short u) {
  union { unsigned u; float f; } v; v.u = ((unsigned)(unsigned short)u) << 16;
  return v.f;
}

// ---------------------------------------------------------------- init: zero deg + W prep (one launch)
// blocks [0, ZBLK): deg[i] = 0
// blocks [ZBLK, ZBLK+16): transpose-convert Wl1|Wr1 f32 [128k][128c] -> bf16 [256c][128k]

__global__ __launch_bounds__(256) void init_kernel(
    int* __restrict__ deg,
    const float* __restrict__ Wl, const float* __restrict__ Wr, short* __restrict__ Wbf) {
  int b = blockIdx.x;
  if (b < ZBLK) {
    int i = b * 256 + threadIdx.x;
    if (i < N_NODES) deg[i] = 0;
  } else {
    int gid = (b - ZBLK) * 256 + threadIdx.x;   // 4096 threads: 256 cols x 16 k-chunks
    int c = gid >> 4, k8 = (gid & 15) * 8;
    const float* W = (c < 128) ? Wl : Wr;
    int cc = c & 127;
    short8 o;
    #pragma unroll
    for (int j = 0; j < 8; ++j) o[j] = f2bf(W[(size_t)(k8 + j) * 128 + cc]);
    *(short8*)(Wbf + (size_t)c * 128 + k8) = o;
  }
}

// ---------------------------------------------------------------- layer 1 GEMM + ELL build, one launch
// blocks [0, GBLK): MFMA GEMM (As staged once, Bs restaged per half Wl/Wr)
// blocks [GBLK, GBLK+EBLK): scatter edges into ell[dst*64 + slot]

#define LSWZ(row, k) (((row) * 128 + (k)) ^ (((row) & 7) << 3))

__global__ __launch_bounds__(256) void gemm_build(
    const float* __restrict__ x, const short* __restrict__ Wbf,
    const float* __restrict__ bl, const float* __restrict__ br,
    short* __restrict__ xl, short* __restrict__ xr,
    const int* __restrict__ ei, int* __restrict__ deg, int* __restrict__ ell) {
  __shared__ short As[128 * 128];
  __shared__ short Bs[128 * 128];
  int t = threadIdx.x;

  if (blockIdx.x >= GBLK) {            // ---- edge scatter part
    int e = (blockIdx.x - GBLK) * 256 + t;
    if (e < E_TOT) {
      int s, d;
      if (e < N_EDGES) { s = ei[e]; d = ei[N_EDGES + e]; }
      else             { s = e - N_EDGES; d = s; }
      int pos = atomicAdd(&deg[d], 1);
      ell[d * MAXD + pos] = s;
    }
    return;
  }

  // ---- GEMM part
  int row0 = blockIdx.x * 128;

  #pragma unroll
  for (int i = 0; i < 8; ++i) {
    int c = t + 256 * i;               // 2048 chunks of 8 elems
    int r = c >> 4, k8 = (c & 15) * 8;
    int gr = row0 + r;
    short8 o = {};
    if (gr < N_NODES) {
      const float* p = x + (size_t)gr * 128 + k8;
      f32x4 a = *(const f32x4*)p, b = *(const f32x4*)(p + 4);
      o[0] = f2bf(a.x); o[1] = f2bf(a.y); o[2] = f2bf(a.z); o[3] = f2bf(a.w);
      o[4] = f2bf(b.x); o[5] = f2bf(b.y); o[6] = f2bf(b.z); o[7] = f2bf(b.w);
    }
    *(short8*)(&As[LSWZ(r, k8)]) = o;
  }

  int w = t >> 6, lane = t & 63;
  int wm = (w >> 1) * 64, wn = (w & 1) * 64;
  int lr = lane & 15, lk = (lane >> 4) * 8;

  for (int hb = 0; hb < 2; ++hb) {
    #pragma unroll
    for (int i = 0; i < 8; ++i) {
      int c = t + 256 * i;
      int col = c >> 4, k8 = (c & 15) * 8;
      short8 o = *(const short8*)(Wbf + (size_t)(hb * 128 + col) * 128 + k8);
      *(short8*)(&Bs[LSWZ(col, k8)]) = o;
    }
    __syncthreads();

    f32x4 acc[4][4];
    #pragma unroll
    for (int m = 0; m < 4; ++m)
      #pragma unroll
      for (int n = 0; n < 4; ++n) acc[m][n] = (f32x4){0.f, 0.f, 0.f, 0.f};

    #pragma unroll
    for (int ks = 0; ks < 4; ++ks) {
      int k0 = ks * 32 + lk;
      short8 af[4], bfr[4];
      #pragma unroll
      for (int m = 0; m < 4; ++m) {
        int r = wm + m * 16 + lr;
        af[m] = *(const short8*)(&As[LSWZ(r, k0)]);
      }
      #pragma unroll
      for (int n = 0; n < 4; ++n) {
        int r = wn + n * 16 + lr;
        bfr[n] = *(const short8*)(&Bs[LSWZ(r, k0)]);
      }
      #pragma unroll
      for (int m = 0; m < 4; ++m)
        #pragma unroll
        for (int n = 0; n < 4; ++n)
          acc[m][n] = __builtin_amdgcn_mfma_f32_16x16x32_bf16(af[m], bfr[n], acc[m][n], 0, 0, 0);
    }

    const float* B0 = hb ? br : bl;
    short* O = hb ? xr : xl;
    int orow = (lane >> 4) * 4;
    #pragma unroll
    for (int n = 0; n < 4; ++n) {
      int col = wn + n * 16 + lr;
      float bv = B0[col];
      #pragma unroll
      for (int m = 0; m < 4; ++m) {
        #pragma unroll
        for (int r = 0; r < 4; ++r) {
          int grow = row0 + wm + m * 16 + orow + r;
          if (grow < N_NODES) O[(size_t)grow * 128 + col] = f2bf(acc[m][n][r] + bv);
        }
      }
    }
    __syncthreads();   // all waves done reading Bs before restage
  }
}

// ---------------------------------------------------------------- layer 1 attention+aggregation fused with layer-2 GEMV
// 16 lanes per node. Per 8-edge tile: gathers go global->LDS via
// global_load_lds (per-lane global addr, wave-uniform LDS dest, zero VGPR for
// in-flight rows). Wave-private LDS slots: no __syncthreads, just vmcnt.

__global__ __launch_bounds__(256) void agg1_fused(
    const short* __restrict__ xl1, const short* __restrict__ xr1,
    const float* __restrict__ att, const float* __restrict__ bias,
    const float* __restrict__ Wl2, const float* __restrict__ bl2,
    const float* __restrict__ Wr2, const float* __restrict__ br2,
    const int* __restrict__ deg, const int* __restrict__ ell,
    float* __restrict__ xl2, float* __restrict__ xr2) {
  __shared__ short sbuf[4][8][512];    // [wave][slot][64 lanes x 8 shorts] = 32 KB
  int gid = blockIdx.x * 256 + threadIdx.x;
  int node = gid >> 4;                 // grid exact: 3125 blocks * 16 nodes
  int t = threadIdx.x;
  int wid = t >> 6, lane = t & 63;
  int L = lane & 15;
  int gbase = lane & 48;               // wave-lane base of this 16-lane group

  short8 xr8 = *(const short8*)(xr1 + (size_t)node * 128 + L * 8);
  float xr[8], at[8];
  #pragma unroll
  for (int r = 0; r < 8; ++r) xr[r] = bf2f(xr8[r]);
  *(float4*)(at)     = *(const float4*)(att + L * 8);
  *(float4*)(at + 4) = *(const float4*)(att + L * 8 + 4);

  float m = -1e30f, denom = 0.f;
  float acc[8];
  #pragma unroll
  for (int r = 0; r < 8; ++r) acc[r] = 0.f;

  int p1 = deg[node];
  const int* erow = ell + (size_t)node * MAXD;

  for (int base = 0; base < p1; base += 8) {
    // ONE coalesced index load: lane L holds edge (base+L)'s src for its node
    int pE = base + L;
    int myidx = erow[pE < p1 ? pE : p1 - 1];
    // 8 gathers global->LDS, all in flight, zero VGPR held
    #pragma unroll
    for (int j = 0; j < 8; ++j) {
      int ij = __shfl(myidx, gbase + j);
      const short* gp = xl1 + (size_t)ij * 128 + L * 8;
      __builtin_amdgcn_global_load_lds(
          (const __attribute__((address_space(1))) void*)gp,
          (__attribute__((address_space(3))) void*)&sbuf[wid][j][0],
          16, 0, 0);
    }
    asm volatile("s_waitcnt vmcnt(0)" ::: "memory");
    __builtin_amdgcn_sched_barrier(0);

    // 8 alpha dots (read own 16B slice back from LDS)
    float pa[8];
    #pragma unroll
    for (int j = 0; j < 8; ++j) {
      short8 v = *(const short8*)(&sbuf[wid][j][lane * 8]);
      float s = 0.f;
      #pragma unroll
      for (int r = 0; r < 8; ++r) {
        float e = bf2f(v[r]) + xr[r];
        e = fmaxf(e, 0.2f * e);          // leaky_relu 0.2, exact
        s = fmaf(e, at[r], s);
      }
      pa[j] = s;
    }
    // pipelined shuffle reductions (24 independent DS ops)
    #pragma unroll
    for (int st = 1; st < 8; st <<= 1) {
      #pragma unroll
      for (int j = 0; j < 8; ++j) pa[j] += __shfl_xor(pa[j], st);
    }
    // mask padded slots branchlessly (exp underflows to exact 0)
    #pragma unroll
    for (int j = 0; j < 8; ++j) pa[j] = (base + j < p1) ? pa[j] : -1e30f;
    // ONE online-softmax fold per tile
    float bm = pa[0];
    #pragma unroll
    for (int j = 1; j < 8; ++j) bm = fmaxf(bm, pa[j]);
    float mnew  = fmaxf(m, bm);
    float scale = __expf(m - mnew);
    float wgt[8], dsum = 0.f;
    #pragma unroll
    for (int j = 0; j < 8; ++j) { wgt[j] = __expf(pa[j] - mnew); dsum += wgt[j]; }
    denom = denom * scale + dsum;
    #pragma unroll
    for (int r = 0; r < 8; ++r) acc[r] *= scale;
    #pragma unroll
    for (int j = 0; j < 8; ++j) {
      short8 v = *(const short8*)(&sbuf[wid][j][lane * 8]);
      #pragma unroll
      for (int r = 0; r < 8; ++r) acc[r] = fmaf(wgt[j], bf2f(v[r]), acc[r]);
    }
    m = mnew;
  }

  float inv = 1.f / (denom + 1e-16f);
  float o[8];
  #pragma unroll
  for (int r = 0; r < 8; ++r) {
    float v = acc[r] * inv + bias[L * 8 + r];
    o[r] = fmaxf(v, 0.01f * v);         // post-layer LeakyReLU(0.01), exact
  }
  // fused layer-2 linear: lane L holds h[L*8 .. L*8+7]
  float pl[4] = {0.f, 0.f, 0.f, 0.f}, pr[4] = {0.f, 0.f, 0.f, 0.f};
  #pragma unroll
  for (int r = 0; r < 8; ++r) {
    float4 wl = *(const float4*)(Wl2 + (size_t)(L * 8 + r) * 4);
    float4 wr = *(const float4*)(Wr2 + (size_t)(L * 8 + r) * 4);
    pl[0] += o[r] * wl.x;  pl[1] += o[r] * wl.y;  pl[2] += o[r] * wl.z;  pl[3] += o[r] * wl.w;
    pr[0] += o[r] * wr.x;  pr[1] += o[r] * wr.y;  pr[2] += o[r] * wr.z;  pr[3] += o[r] * wr.w;
  }
  #pragma unroll
  for (int off = 1; off < 16; off <<= 1) {
    #pragma unroll
    for (int c = 0; c < 4; ++c) {
      pl[c] += __shfl_xor(pl[c], off);
      pr[c] += __shfl_xor(pr[c], off);
    }
  }
  if (L == 0) {
    float4 b0 = *(const float4*)(bl2);
    float4 b1 = *(const float4*)(br2);
    *(float4*)(xl2 + (size_t)node * 4) =
        make_float4(pl[0] + b0.x, pl[1] + b0.y, pl[2] + b0.z, pl[3] + b0.w);
    *(float4*)(xr2 + (size_t)node * 4) =
        make_float4(pr[0] + b1.x, pr[1] + b1.y, pr[2] + b1.z, pr[3] + b1.w);
  }
}

// ---------------------------------------------------------------- layer 2 attention + final softmax

__global__ __launch_bounds__(256) void agg2_kernel(
    const float* __restrict__ xl2, const float* __restrict__ xr2,
    const float* __restrict__ att, const float* __restrict__ bias,
    const int* __restrict__ deg, const int* __restrict__ ell,
    float* __restrict__ out) {
  int gid = blockIdx.x * 256 + threadIdx.x;
  int node = gid >> 4;
  if (node >= N_NODES) return;
  int L = threadIdx.x & 15;
  float4 xr = *(const float4*)(xr2 + (size_t)node * 4);
  float4 at = *(const float4*)(att);
  float m = -1e30f, denom = 0.f;
  float4 acc = make_float4(0.f, 0.f, 0.f, 0.f);
  int p1 = deg[node];
  const int* erow = ell + (size_t)node * MAXD;
  int nit = (p1 + 15) >> 4;
  int p = L;
  for (int it = 0; it < nit; ++it) {
    bool valid = p < p1;
    int s = erow[valid ? p : p1 - 1];
    float4 xv = *(const float4*)(xl2 + (size_t)s * 4);
    float e0 = xv.x + xr.x; e0 = fmaxf(e0, 0.2f * e0);
    float e1 = xv.y + xr.y; e1 = fmaxf(e1, 0.2f * e1);
    float e2 = xv.z + xr.z; e2 = fmaxf(e2, 0.2f * e2);
    float e3 = xv.w + xr.w; e3 = fmaxf(e3, 0.2f * e3);
    float pa = e0 * at.x + e1 * at.y + e2 * at.z + e3 * at.w;
    pa = valid ? pa : -1e30f;
    float mnew  = fmaxf(m, pa);
    float scale = __expf(m - mnew);
    float wgt   = __expf(pa - mnew);    // exact 0 for padded slots
    denom = denom * scale + wgt;
    acc.x = acc.x * scale + wgt * xv.x;
    acc.y = acc.y * scale + wgt * xv.y;
    acc.z = acc.z * scale + wgt * xv.z;
    acc.w = acc.w * scale + wgt * xv.w;
    m = mnew;
    p += 16;
  }
  #pragma unroll
  for (int off = 1; off < 16; off <<= 1) {
    float mo = __shfl_xor(m, off);
    float dn = __shfl_xor(denom, off);
    float ax = __shfl_xor(acc.x, off);
    float ay = __shfl_xor(acc.y, off);
    float az = __shfl_xor(acc.z, off);
    float aw = __shfl_xor(acc.w, off);
    float mnew = fmaxf(m, mo);
    float sa = __expf(m - mnew);
    float sb = __expf(mo - mnew);
    denom = denom * sa + dn * sb;
    acc.x = acc.x * sa + ax * sb;
    acc.y = acc.y * sa + ay * sb;
    acc.z = acc.z * sa + az * sb;
    acc.w = acc.w * sa + aw * sb;
    m = mnew;
  }
  if (L == 0) {
    float inv = 1.f / (denom + 1e-16f);
    float4 b = *(const float4*)(bias);
    float o0 = acc.x * inv + b.x;
    float o1 = acc.y * inv + b.y;
    float o2 = acc.z * inv + b.z;
    float o3 = acc.w * inv + b.w;
    float mx = fmaxf(fmaxf(o0, o1), fmaxf(o2, o3));
    float q0 = __expf(o0 - mx), q1 = __expf(o1 - mx), q2 = __expf(o2 - mx), q3 = __expf(o3 - mx);
    float r = 1.f / (q0 + q1 + q2 + q3);
    *(float4*)(out + (size_t)node * 4) = make_float4(q0 * r, q1 * r, q2 * r, q3 * r);
  }
}

// ---------------------------------------------------------------- launch (4 dispatches total)

extern "C" void kernel_launch(void* const* d_in, const int* in_sizes, int n_in,
                              void* d_out, int out_size, void* d_ws, size_t ws_size,
                              hipStream_t stream) {
  (void)in_sizes; (void)n_in; (void)out_size; (void)ws_size;
  const float* x     = (const float*)d_in[0];
  const int*   ei    = (const int*)d_in[1];
  const float* Wl1   = (const float*)d_in[3];
  const float* bl1   = (const float*)d_in[4];
  const float* Wr1   = (const float*)d_in[5];
  const float* br1   = (const float*)d_in[6];
  const float* att1  = (const float*)d_in[7];
  const float* bias1 = (const float*)d_in[8];
  const float* Wl2   = (const float*)d_in[9];
  const float* bl2   = (const float*)d_in[10];
  const float* Wr2   = (const float*)d_in[11];
  const float* br2   = (const float*)d_in[12];
  const float* att2  = (const float*)d_in[13];
  const float* bias2 = (const float*)d_in[14];
  float* out = (float*)d_out;

  char* w = (char*)d_ws;
  auto alloc = [&](size_t bytes) -> char* {
    char* p = w;
    w += (bytes + 255) & ~(size_t)255;
    return p;
  };
  short* xl1    = (short*)alloc((size_t)N_NODES * 128 * 2);
  short* xr1    = (short*)alloc((size_t)N_NODES * 128 * 2);
  float* xl2    = (float*)alloc((size_t)N_NODES * 4 * 4);
  float* xr2    = (float*)alloc((size_t)N_NODES * 4 * 4);
  int*   deg    = (int*)alloc((size_t)N_NODES * 4);
  int*   ell    = (int*)alloc((size_t)N_NODES * MAXD * 4);
  short* Wbf    = (short*)alloc((size_t)256 * 128 * 2);

  init_kernel<<<ZBLK + 16, 256, 0, stream>>>(deg, Wl1, Wr1, Wbf);
  gemm_build<<<GBLK + EBLK, 256, 0, stream>>>(x, Wbf, bl1, br1, xl1, xr1, ei, deg, ell);
  agg1_fused<<<(N_NODES * 16 + 255) / 256, 256, 0, stream>>>(
      xl1, xr1, att1, bias1, Wl2, bl2, Wr2, br2, deg, ell, xl2, xr2);
  agg2_kernel<<<(N_NODES * 16 + 255) / 256, 256, 0, stream>>>(
      xl2, xr2, att2, bias2, deg, ell, out);
}

// Round 14
// 124.534 us; speedup vs baseline: 1.4153x; 1.0292x over previous
//
#include <hip/hip_runtime.h>

#define N_NODES 50000
#define N_EDGES 600000
#define E_TOT   650000   // edges + self loops
#define EBLK    2540     // ceil(E_TOT/256)
#define GBLK    391      // ceil(N_NODES/128) gemm blocks
#define ZBLK    196      // ceil(N_NODES/256) deg-zero blocks
#define MAXD    64       // ELL stride; max in-degree ~ Poisson(12)+1 << 64

typedef __attribute__((ext_vector_type(8))) short short8;
typedef __attribute__((ext_vector_type(4))) float f32x4;

__device__ inline short f2bf(float f) {           // round-to-nearest-even f32->bf16
  union { float f; unsigned u; } v; v.f = f;
  unsigned r = (v.u + 0x7FFFu + ((v.u >> 16) & 1u)) >> 16;
  return (short)r;
}
__device__ inline float bf2f(short u) {
  union { unsigned u; float f; } v; v.u = ((unsigned)(unsigned short)u) << 16;
  return v.f;
}

// ---------------------------------------------------------------- init: zero deg + W prep (one launch)
// blocks [0, ZBLK): deg[i] = 0
// blocks [ZBLK, ZBLK+16): transpose-convert Wl1|Wr1 f32 [128k][128c] -> bf16 [256c][128k]

__global__ __launch_bounds__(256) void init_kernel(
    int* __restrict__ deg,
    const float* __restrict__ Wl, const float* __restrict__ Wr, short* __restrict__ Wbf) {
  int b = blockIdx.x;
  if (b < ZBLK) {
    int i = b * 256 + threadIdx.x;
    if (i < N_NODES) deg[i] = 0;
  } else {
    int gid = (b - ZBLK) * 256 + threadIdx.x;   // 4096 threads: 256 cols x 16 k-chunks
    int c = gid >> 4, k8 = (gid & 15) * 8;
    const float* W = (c < 128) ? Wl : Wr;
    int cc = c & 127;
    short8 o;
    #pragma unroll
    for (int j = 0; j < 8; ++j) o[j] = f2bf(W[(size_t)(k8 + j) * 128 + cc]);
    *(short8*)(Wbf + (size_t)c * 128 + k8) = o;
  }
}

// ---------------------------------------------------------------- layer 1 GEMM + ELL build, one launch
// blocks [0, GBLK): LDS-FREE MFMA GEMM — A fragments in registers (direct
// global f32 loads + inline bf16 convert, reused across both W halves);
// B fragments direct from L2-resident Wbf. No __shared__, no barriers.
// blocks [GBLK, GBLK+EBLK): scatter edges into ell[dst*64 + slot]

__global__ __launch_bounds__(256) void gemm_build(
    const float* __restrict__ x, const short* __restrict__ Wbf,
    const float* __restrict__ bl, const float* __restrict__ br,
    short* __restrict__ xl, short* __restrict__ xr,
    const int* __restrict__ ei, int* __restrict__ deg, int* __restrict__ ell) {
  int t = threadIdx.x;

  if (blockIdx.x >= GBLK) {            // ---- edge scatter part (no LDS reserved)
    int e = (blockIdx.x - GBLK) * 256 + t;
    if (e < E_TOT) {
      int s, d;
      if (e < N_EDGES) { s = ei[e]; d = ei[N_EDGES + e]; }
      else             { s = e - N_EDGES; d = s; }
      int pos = atomicAdd(&deg[d], 1);
      ell[d * MAXD + pos] = s;
    }
    return;
  }

  // ---- GEMM part
  int row0 = blockIdx.x * 128;
  int w = t >> 6, lane = t & 63;
  int wm = (w >> 1) * 64, wn = (w & 1) * 64;
  int lr = lane & 15, lk = (lane >> 4) * 8;

  // A fragments: rows wm+m*16+lr, k = ks*32+lk..+8, f32 -> bf16 inline.
  // OOB rows clamp to row N-1 (their outputs are masked at the store).
  short8 af[4][4];                     // [ks][m] = 64 VGPR
  #pragma unroll
  for (int ks = 0; ks < 4; ++ks) {
    #pragma unroll
    for (int m = 0; m < 4; ++m) {
      int gr = row0 + wm + m * 16 + lr;
      gr = gr < N_NODES ? gr : N_NODES - 1;
      const float* p = x + (size_t)gr * 128 + ks * 32 + lk;
      f32x4 a = *(const f32x4*)p, b = *(const f32x4*)(p + 4);
      short8 o;
      o[0] = f2bf(a.x); o[1] = f2bf(a.y); o[2] = f2bf(a.z); o[3] = f2bf(a.w);
      o[4] = f2bf(b.x); o[5] = f2bf(b.y); o[6] = f2bf(b.z); o[7] = f2bf(b.w);
      af[ks][m] = o;
    }
  }

  #pragma unroll
  for (int hb = 0; hb < 2; ++hb) {
    f32x4 acc[4][4];
    #pragma unroll
    for (int m = 0; m < 4; ++m)
      #pragma unroll
      for (int n = 0; n < 4; ++n) acc[m][n] = (f32x4){0.f, 0.f, 0.f, 0.f};

    #pragma unroll
    for (int ks = 0; ks < 4; ++ks) {
      short8 bfr[4];
      #pragma unroll
      for (int n = 0; n < 4; ++n) {
        int col = hb * 128 + wn + n * 16 + lr;
        bfr[n] = *(const short8*)(Wbf + (size_t)col * 128 + ks * 32 + lk);
      }
      #pragma unroll
      for (int m = 0; m < 4; ++m)
        #pragma unroll
        for (int n = 0; n < 4; ++n)
          acc[m][n] = __builtin_amdgcn_mfma_f32_16x16x32_bf16(af[ks][m], bfr[n], acc[m][n], 0, 0, 0);
    }

    const float* B0 = hb ? br : bl;
    short* O = hb ? xr : xl;
    int orow = (lane >> 4) * 4;
    #pragma unroll
    for (int n = 0; n < 4; ++n) {
      int col = wn + n * 16 + lr;
      float bv = B0[col];
      #pragma unroll
      for (int m = 0; m < 4; ++m) {
        #pragma unroll
        for (int r = 0; r < 4; ++r) {
          int grow = row0 + wm + m * 16 + orow + r;
          if (grow < N_NODES) O[(size_t)grow * 128 + col] = f2bf(acc[m][n][r] + bv);
        }
      }
    }
  }
}

// ---------------------------------------------------------------- layer 1 attention+aggregation fused with layer-2 GEMV
// 16 lanes per node. Per 8-edge tile: gathers go global->LDS via
// global_load_lds (per-lane global addr, wave-uniform LDS dest, zero VGPR for
// in-flight rows). Wave-private LDS slots: no __syncthreads, just vmcnt.

__global__ __launch_bounds__(256) void agg1_fused(
    const short* __restrict__ xl1, const short* __restrict__ xr1,
    const float* __restrict__ att, const float* __restrict__ bias,
    const float* __restrict__ Wl2, const float* __restrict__ bl2,
    const float* __restrict__ Wr2, const float* __restrict__ br2,
    const int* __restrict__ deg, const int* __restrict__ ell,
    float* __restrict__ xl2, float* __restrict__ xr2) {
  __shared__ short sbuf[4][8][512];    // [wave][slot][64 lanes x 8 shorts] = 32 KB
  int gid = blockIdx.x * 256 + threadIdx.x;
  int node = gid >> 4;                 // grid exact: 3125 blocks * 16 nodes
  int t = threadIdx.x;
  int wid = t >> 6, lane = t & 63;
  int L = lane & 15;
  int gbase = lane & 48;               // wave-lane base of this 16-lane group

  short8 xr8 = *(const short8*)(xr1 + (size_t)node * 128 + L * 8);
  float xr[8], at[8];
  #pragma unroll
  for (int r = 0; r < 8; ++r) xr[r] = bf2f(xr8[r]);
  *(float4*)(at)     = *(const float4*)(att + L * 8);
  *(float4*)(at + 4) = *(const float4*)(att + L * 8 + 4);

  float m = -1e30f, denom = 0.f;
  float acc[8];
  #pragma unroll
  for (int r = 0; r < 8; ++r) acc[r] = 0.f;

  int p1 = deg[node];
  const int* erow = ell + (size_t)node * MAXD;

  for (int base = 0; base < p1; base += 8) {
    // ONE coalesced index load: lane L holds edge (base+L)'s src for its node
    int pE = base + L;
    int myidx = erow[pE < p1 ? pE : p1 - 1];
    // 8 gathers global->LDS, all in flight, zero VGPR held
    #pragma unroll
    for (int j = 0; j < 8; ++j) {
      int ij = __shfl(myidx, gbase + j);
      const short* gp = xl1 + (size_t)ij * 128 + L * 8;
      __builtin_amdgcn_global_load_lds(
          (const __attribute__((address_space(1))) void*)gp,
          (__attribute__((address_space(3))) void*)&sbuf[wid][j][0],
          16, 0, 0);
    }
    asm volatile("s_waitcnt vmcnt(0)" ::: "memory");
    __builtin_amdgcn_sched_barrier(0);

    // 8 alpha dots (read own 16B slice back from LDS)
    float pa[8];
    #pragma unroll
    for (int j = 0; j < 8; ++j) {
      short8 v = *(const short8*)(&sbuf[wid][j][lane * 8]);
      float s = 0.f;
      #pragma unroll
      for (int r = 0; r < 8; ++r) {
        float e = bf2f(v[r]) + xr[r];
        e = fmaxf(e, 0.2f * e);          // leaky_relu 0.2, exact
        s = fmaf(e, at[r], s);
      }
      pa[j] = s;
    }
    // pipelined shuffle reductions (24 independent DS ops)
    #pragma unroll
    for (int st = 1; st < 8; st <<= 1) {
      #pragma unroll
      for (int j = 0; j < 8; ++j) pa[j] += __shfl_xor(pa[j], st);
    }
    // mask padded slots branchlessly (exp underflows to exact 0)
    #pragma unroll
    for (int j = 0; j < 8; ++j) pa[j] = (base + j < p1) ? pa[j] : -1e30f;
    // ONE online-softmax fold per tile
    float bm = pa[0];
    #pragma unroll
    for (int j = 1; j < 8; ++j) bm = fmaxf(bm, pa[j]);
    float mnew  = fmaxf(m, bm);
    float scale = __expf(m - mnew);
    float wgt[8], dsum = 0.f;
    #pragma unroll
    for (int j = 0; j < 8; ++j) { wgt[j] = __expf(pa[j] - mnew); dsum += wgt[j]; }
    denom = denom * scale + dsum;
    #pragma unroll
    for (int r = 0; r < 8; ++r) acc[r] *= scale;
    #pragma unroll
    for (int j = 0; j < 8; ++j) {
      short8 v = *(const short8*)(&sbuf[wid][j][lane * 8]);
      #pragma unroll
      for (int r = 0; r < 8; ++r) acc[r] = fmaf(wgt[j], bf2f(v[r]), acc[r]);
    }
    m = mnew;
  }

  float inv = 1.f / (denom + 1e-16f);
  float o[8];
  #pragma unroll
  for (int r = 0; r < 8; ++r) {
    float v = acc[r] * inv + bias[L * 8 + r];
    o[r] = fmaxf(v, 0.01f * v);         // post-layer LeakyReLU(0.01), exact
  }
  // fused layer-2 linear: lane L holds h[L*8 .. L*8+7]
  float pl[4] = {0.f, 0.f, 0.f, 0.f}, pr[4] = {0.f, 0.f, 0.f, 0.f};
  #pragma unroll
  for (int r = 0; r < 8; ++r) {
    float4 wl = *(const float4*)(Wl2 + (size_t)(L * 8 + r) * 4);
    float4 wr = *(const float4*)(Wr2 + (size_t)(L * 8 + r) * 4);
    pl[0] += o[r] * wl.x;  pl[1] += o[r] * wl.y;  pl[2] += o[r] * wl.z;  pl[3] += o[r] * wl.w;
    pr[0] += o[r] * wr.x;  pr[1] += o[r] * wr.y;  pr[2] += o[r] * wr.z;  pr[3] += o[r] * wr.w;
  }
  #pragma unroll
  for (int off = 1; off < 16; off <<= 1) {
    #pragma unroll
    for (int c = 0; c < 4; ++c) {
      pl[c] += __shfl_xor(pl[c], off);
      pr[c] += __shfl_xor(pr[c], off);
    }
  }
  if (L == 0) {
    float4 b0 = *(const float4*)(bl2);
    float4 b1 = *(const float4*)(br2);
    *(float4*)(xl2 + (size_t)node * 4) =
        make_float4(pl[0] + b0.x, pl[1] + b0.y, pl[2] + b0.z, pl[3] + b0.w);
    *(float4*)(xr2 + (size_t)node * 4) =
        make_float4(pr[0] + b1.x, pr[1] + b1.y, pr[2] + b1.z, pr[3] + b1.w);
  }
}

// ---------------------------------------------------------------- layer 2 attention + final softmax

__global__ __launch_bounds__(256) void agg2_kernel(
    const float* __restrict__ xl2, const float* __restrict__ xr2,
    const float* __restrict__ att, const float* __restrict__ bias,
    const int* __restrict__ deg, const int* __restrict__ ell,
    float* __restrict__ out) {
  int gid = blockIdx.x * 256 + threadIdx.x;
  int node = gid >> 4;
  if (node >= N_NODES) return;
  int L = threadIdx.x & 15;
  float4 xr = *(const float4*)(xr2 + (size_t)node * 4);
  float4 at = *(const float4*)(att);
  float m = -1e30f, denom = 0.f;
  float4 acc = make_float4(0.f, 0.f, 0.f, 0.f);
  int p1 = deg[node];
  const int* erow = ell + (size_t)node * MAXD;
  int nit = (p1 + 15) >> 4;
  int p = L;
  for (int it = 0; it < nit; ++it) {
    bool valid = p < p1;
    int s = erow[valid ? p : p1 - 1];
    float4 xv = *(const float4*)(xl2 + (size_t)s * 4);
    float e0 = xv.x + xr.x; e0 = fmaxf(e0, 0.2f * e0);
    float e1 = xv.y + xr.y; e1 = fmaxf(e1, 0.2f * e1);
    float e2 = xv.z + xr.z; e2 = fmaxf(e2, 0.2f * e2);
    float e3 = xv.w + xr.w; e3 = fmaxf(e3, 0.2f * e3);
    float pa = e0 * at.x + e1 * at.y + e2 * at.z + e3 * at.w;
    pa = valid ? pa : -1e30f;
    float mnew  = fmaxf(m, pa);
    float scale = __expf(m - mnew);
    float wgt   = __expf(pa - mnew);    // exact 0 for padded slots
    denom = denom * scale + wgt;
    acc.x = acc.x * scale + wgt * xv.x;
    acc.y = acc.y * scale + wgt * xv.y;
    acc.z = acc.z * scale + wgt * xv.z;
    acc.w = acc.w * scale + wgt * xv.w;
    m = mnew;
    p += 16;
  }
  #pragma unroll
  for (int off = 1; off < 16; off <<= 1) {
    float mo = __shfl_xor(m, off);
    float dn = __shfl_xor(denom, off);
    float ax = __shfl_xor(acc.x, off);
    float ay = __shfl_xor(acc.y, off);
    float az = __shfl_xor(acc.z, off);
    float aw = __shfl_xor(acc.w, off);
    float mnew = fmaxf(m, mo);
    float sa = __expf(m - mnew);
    float sb = __expf(mo - mnew);
    denom = denom * sa + dn * sb;
    acc.x = acc.x * sa + ax * sb;
    acc.y = acc.y * sa + ay * sb;
    acc.z = acc.z * sa + az * sb;
    acc.w = acc.w * sa + aw * sb;
    m = mnew;
  }
  if (L == 0) {
    float inv = 1.f / (denom + 1e-16f);
    float4 b = *(const float4*)(bias);
    float o0 = acc.x * inv + b.x;
    float o1 = acc.y * inv + b.y;
    float o2 = acc.z * inv + b.z;
    float o3 = acc.w * inv + b.w;
    float mx = fmaxf(fmaxf(o0, o1), fmaxf(o2, o3));
    float q0 = __expf(o0 - mx), q1 = __expf(o1 - mx), q2 = __expf(o2 - mx), q3 = __expf(o3 - mx);
    float r = 1.f / (q0 + q1 + q2 + q3);
    *(float4*)(out + (size_t)node * 4) = make_float4(q0 * r, q1 * r, q2 * r, q3 * r);
  }
}

// ---------------------------------------------------------------- launch (4 dispatches total)

extern "C" void kernel_launch(void* const* d_in, const int* in_sizes, int n_in,
                              void* d_out, int out_size, void* d_ws, size_t ws_size,
                              hipStream_t stream) {
  (void)in_sizes; (void)n_in; (void)out_size; (void)ws_size;
  const float* x     = (const float*)d_in[0];
  const int*   ei    = (const int*)d_in[1];
  const float* Wl1   = (const float*)d_in[3];
  const float* bl1   = (const float*)d_in[4];
  const float* Wr1   = (const float*)d_in[5];
  const float* br1   = (const float*)d_in[6];
  const float* att1  = (const float*)d_in[7];
  const float* bias1 = (const float*)d_in[8];
  const float* Wl2   = (const float*)d_in[9];
  const float* bl2   = (const float*)d_in[10];
  const float* Wr2   = (const float*)d_in[11];
  const float* br2   = (const float*)d_in[12];
  const float* att2  = (const float*)d_in[13];
  const float* bias2 = (const float*)d_in[14];
  float* out = (float*)d_out;

  char* w = (char*)d_ws;
  auto alloc = [&](size_t bytes) -> char* {
    char* p = w;
    w += (bytes + 255) & ~(size_t)255;
    return p;
  };
  short* xl1    = (short*)alloc((size_t)N_NODES * 128 * 2);
  short* xr1    = (short*)alloc((size_t)N_NODES * 128 * 2);
  float* xl2    = (float*)alloc((size_t)N_NODES * 4 * 4);
  float* xr2    = (float*)alloc((size_t)N_NODES * 4 * 4);
  int*   deg    = (int*)alloc((size_t)N_NODES * 4);
  int*   ell    = (int*)alloc((size_t)N_NODES * MAXD * 4);
  short* Wbf    = (short*)alloc((size_t)256 * 128 * 2);

  init_kernel<<<ZBLK + 16, 256, 0, stream>>>(deg, Wl1, Wr1, Wbf);
  gemm_build<<<GBLK + EBLK, 256, 0, stream>>>(x, Wbf, bl1, br1, xl1, xr1, ei, deg, ell);
  agg1_fused<<<(N_NODES * 16 + 255) / 256, 256, 0, stream>>>(
      xl1, xr1, att1, bias1, Wl2, bl2, Wr2, br2, deg, ell, xl2, xr2);
  agg2_kernel<<<(N_NODES * 16 + 255) / 256, 256, 0, stream>>>(
      xl2, xr2, att2, bias2, deg, ell, out);
}